// Round 8
// baseline (453.879 us; speedup 1.0000x reference)
//
#include <hip/hip_runtime.h>
#include <hip/hip_bf16.h>

#define NTOK 8192
#define HID 2048
#define INTER 768
#define NEXP 16

typedef __bf16 bf16x8 __attribute__((ext_vector_type(8)));
typedef float f32x4 __attribute__((ext_vector_type(4)));

typedef const __attribute__((address_space(1))) void gvoid_t;
typedef __attribute__((address_space(3))) void lvoid_t;

static __device__ __forceinline__ void load_lds16(const void* g, void* l) {
  __builtin_amdgcn_global_load_lds((gvoid_t*)g, (lvoid_t*)l, 16, 0, 0);
}

static __device__ __forceinline__ unsigned short f2bf(float f) {
  unsigned int u = __float_as_uint(f);
  u += 0x7FFFu + ((u >> 16) & 1u);
  return (unsigned short)(u >> 16);
}

static __device__ __forceinline__ float bf2f(unsigned short b) {
  return __uint_as_float(((unsigned int)b) << 16);
}

// Pipeline sync: drain DMA *after* compute phase, raw barrier (no implicit
// per-barrier vmcnt(0) like __syncthreads). T3 minimal recipe.
#define SYNC_PIPE                                     \
  asm volatile("s_waitcnt vmcnt(0)" ::: "memory");    \
  __builtin_amdgcn_s_barrier();

// ---------------- fp32 -> bf16 conversion: all 3 weights in ONE launch ----------------
__global__ __launch_bounds__(256) void cvt3_kernel(
    const float* __restrict__ s0, const float* __restrict__ s1, const float* __restrict__ s2,
    unsigned short* __restrict__ dst0, unsigned short* __restrict__ dst1,
    unsigned short* __restrict__ dst2, int n) {
  const float* src = (blockIdx.y == 0) ? s0 : (blockIdx.y == 1) ? s1 : s2;
  unsigned short* dst = (blockIdx.y == 0) ? dst0 : (blockIdx.y == 1) ? dst1 : dst2;
  int i = (blockIdx.x * 256 + threadIdx.x) * 4;
  int stride = gridDim.x * 256 * 4;
  for (; i < n; i += stride) {
    float4 v = *reinterpret_cast<const float4*>(src + i);
    ushort4 o;
    o.x = f2bf(v.x); o.y = f2bf(v.y); o.z = f2bf(v.z); o.w = f2bf(v.w);
    *reinterpret_cast<ushort4*>(dst + i) = o;
  }
}

// ---------------- router: barrier-free, LDS-free, atomic-free ----------------
__global__ __launch_bounds__(256) void router_kernel(const float* __restrict__ x,
                                                     const float* __restrict__ gw,
                                                     int* __restrict__ te,
                                                     float* __restrict__ tw,
                                                     unsigned short* __restrict__ Xb) {
  const int lane = threadIdx.x & 63;
  const int wid = threadIdx.x >> 6;
  const int t0 = (blockIdx.x * 4 + wid) * 2;  // this wave's two tokens
  const float4* xa = reinterpret_cast<const float4*>(x + (size_t)t0 * HID);
  const float4* xb = xa + HID / 4;
  const float4* g4 = reinterpret_cast<const float4*>(gw);

  float4 va[8], vb[8];
#pragma unroll
  for (int j = 0; j < 8; ++j) {
    va[j] = xa[lane + 64 * j];
    vb[j] = xb[lane + 64 * j];
  }
  ushort4* oa = reinterpret_cast<ushort4*>(Xb + (size_t)t0 * HID);
  ushort4* ob = oa + HID / 4;
#pragma unroll
  for (int j = 0; j < 8; ++j) {
    ushort4 u;
    u.x = f2bf(va[j].x); u.y = f2bf(va[j].y); u.z = f2bf(va[j].z); u.w = f2bf(va[j].w);
    oa[lane + 64 * j] = u;
    u.x = f2bf(vb[j].x); u.y = f2bf(vb[j].y); u.z = f2bf(vb[j].z); u.w = f2bf(vb[j].w);
    ob[lane + 64 * j] = u;
  }

  float accA[NEXP], accB[NEXP];
#pragma unroll
  for (int e = 0; e < NEXP; ++e) { accA[e] = 0.f; accB[e] = 0.f; }
#pragma unroll
  for (int e = 0; e < NEXP; ++e) {
#pragma unroll
    for (int j = 0; j < 8; ++j) {
      float4 g = g4[e * (HID / 4) + lane + 64 * j];
      accA[e] += va[j].x * g.x + va[j].y * g.y + va[j].z * g.z + va[j].w * g.w;
      accB[e] += vb[j].x * g.x + vb[j].y * g.y + vb[j].z * g.z + vb[j].w * g.w;
    }
  }
#pragma unroll
  for (int e = 0; e < NEXP; ++e) {
#pragma unroll
    for (int m = 32; m >= 1; m >>= 1) {
      accA[e] += __shfl_xor(accA[e], m);
      accB[e] += __shfl_xor(accB[e], m);
    }
  }
  if (lane == 0) {
#pragma unroll
    for (int k = 0; k < 2; ++k) {
      const float* acc = k ? accB : accA;
      int t = t0 + k;
      float b0 = -1e30f; int i0 = 0;
#pragma unroll
      for (int e = 0; e < NEXP; ++e) { if (acc[e] > b0) { b0 = acc[e]; i0 = e; } }
      float b1 = -1e30f; int i1 = 0;
#pragma unroll
      for (int e = 0; e < NEXP; ++e) { if (e != i0 && acc[e] > b1) { b1 = acc[e]; i1 = e; } }
      float w0 = 1.f / (1.f + __expf(b1 - b0));
      te[2 * t] = i0; te[2 * t + 1] = i1;
      tw[2 * t] = w0; tw[2 * t + 1] = 1.f - w0;
    }
  }
}

// ---------------- build: histogram + scan + scatter, ONE block, NO atomics ----------------
__global__ __launch_bounds__(256) void build_kernel(
    const int* __restrict__ te, const float* __restrict__ tw,
    int* __restrict__ counts, int* __restrict__ offsets,
    int* __restrict__ tok_flat, float* __restrict__ w_flat,
    int* __restrict__ tok_slot,
    int* __restrict__ tile_map, int* __restrict__ n_tiles) {
  __shared__ int lds_cnt[NEXP][257];
  __shared__ int lds_off[NEXP];
  const int tid = threadIdx.x;
  const int lane = tid & 63;
  const int wv = tid >> 6;

  int cnt[NEXP];
#pragma unroll
  for (int ex = 0; ex < NEXP; ++ex) cnt[ex] = 0;
  for (int i = 0; i < 64; ++i) {
    int e = te[tid * 64 + i];
#pragma unroll
    for (int ex = 0; ex < NEXP; ++ex) cnt[ex] += (e == ex) ? 1 : 0;
  }
#pragma unroll
  for (int ex = 0; ex < NEXP; ++ex) lds_cnt[ex][tid] = cnt[ex];
  __syncthreads();

  for (int ex = wv * 4; ex < wv * 4 + 4; ++ex) {
    int carry = 0;
    for (int c = 0; c < 4; ++c) {
      int v = lds_cnt[ex][c * 64 + lane];
      int s = v;
#pragma unroll
      for (int d = 1; d < 64; d <<= 1) {
        int o = __shfl_up(s, d);
        if (lane >= d) s += o;
      }
      lds_cnt[ex][c * 64 + lane] = carry + s - v;  // exclusive
      carry += __shfl(s, 63);
    }
    if (lane == 0) lds_cnt[ex][256] = carry;
  }
  __syncthreads();

  if (tid == 0) {
    int run = 0, nt = 0;
    for (int e = 0; e < NEXP; ++e) {
      int tot = lds_cnt[e][256];
      counts[e] = tot;
      offsets[e] = run;
      lds_off[e] = run;
      for (int m0 = 0; m0 < tot; m0 += 128) tile_map[nt++] = (e << 16) | m0;
      run += tot;
    }
    *n_tiles = nt;
  }
  __syncthreads();

  int base[NEXP];
#pragma unroll
  for (int ex = 0; ex < NEXP; ++ex) base[ex] = lds_off[ex] + lds_cnt[ex][tid];
  for (int i = 0; i < 64; ++i) {
    int idx = tid * 64 + i;
    int e = te[idx];
    float w = tw[idx];
    int pos = 0;
#pragma unroll
    for (int ex = 0; ex < NEXP; ++ex) {
      if (e == ex) { pos = base[ex]; base[ex] = pos + 1; }
    }
    tok_flat[pos] = idx >> 1;
    w_flat[pos] = w;
    tok_slot[idx] = pos;  // inverse map for combine
  }
}

// ---------------- fused gate+up GEMM: Hf = silu(X Wg^T) * (X Wu^T) ----------------
// Software-pipelined K-loop: STAGE(next 32-half into other buffer set) ->
// COMPUTE(current) -> vmcnt(0) -> raw s_barrier. DMA latency hides under the
// 32-MFMA compute phase (impossible with __syncthreads: it drains vmcnt at
// every barrier). LDS slot-XOR swizzle unchanged (zero conflicts, r2-r7).
__global__ __launch_bounds__(256, 2) void gemm_gu_kernel(
    const unsigned short* __restrict__ Xb,   // [NTOK][HID] bf16
    const unsigned short* __restrict__ Wg,   // [E][INTER][HID] bf16
    const unsigned short* __restrict__ Wu,   // [E][INTER][HID] bf16
    const int* __restrict__ counts, const int* __restrict__ offsets,
    const int* __restrict__ tok_flat,
    const int* __restrict__ tile_map, const int* __restrict__ n_tiles,
    unsigned short* __restrict__ Hf) {       // [2*NTOK][INTER] bf16
  const int bid = blockIdx.x;
  const int cpx = gridDim.x >> 3;            // 864/8 = 108
  const int wg = (bid & 7) * cpx + (bid >> 3);
  const int y = wg / 6;
  if (y >= *n_tiles) return;
  const int xb = wg - y * 6;
  const int tm = tile_map[y];
  const int e = tm >> 16, m0 = tm & 0xFFFF;
  const int cnt = counts[e];
  const int off = offsets[e];
  const int n0 = xb * 128;

  __shared__ __align__(16) unsigned short As0[128 * 32], As1[128 * 32];
  __shared__ __align__(16) unsigned short Bg0[128 * 32], Bg1[128 * 32];
  __shared__ __align__(16) unsigned short Bu0[128 * 32], Bu1[128 * 32];

  const int tid = threadIdx.x;
  const int lane = tid & 63;
  const int wid = tid >> 6;
  const int rl = tid >> 2;                              // staging row 0..63
  const int srcc = ((tid & 3) ^ ((tid >> 3) & 3)) * 8;  // swizzled global slot
  const int d0 = tid * 8;                               // linear LDS dest (ushort idx)
  const int d1 = d0 + 64 * 32;

  const int r0 = m0 + rl, r1 = r0 + 64;
  const int s0 = (r0 < cnt) ? off + r0 : off;
  const int s1 = (r1 < cnt) ? off + r1 : off;
  const unsigned short* aptr0 = Xb + (size_t)tok_flat[s0] * HID + srcc;
  const unsigned short* aptr1 = Xb + (size_t)tok_flat[s1] * HID + srcc;
  const unsigned short* gptr0 = Wg + ((size_t)e * INTER + n0 + rl) * HID + srcc;
  const unsigned short* gptr1 = gptr0 + (size_t)64 * HID;
  const unsigned short* uptr0 = Wu + ((size_t)e * INTER + n0 + rl) * HID + srcc;
  const unsigned short* uptr1 = uptr0 + (size_t)64 * HID;

  f32x4 zero = {0.f, 0.f, 0.f, 0.f};
  f32x4 accG[4][4], accU[4][4];
#pragma unroll
  for (int i = 0; i < 4; ++i)
#pragma unroll
    for (int j = 0; j < 4; ++j) { accG[i][j] = zero; accU[i][j] = zero; }

  const int wm = (wid >> 1) * 64;
  const int wn = (wid & 1) * 64;
  const int fr = lane & 15;
  const int cs = (((lane >> 4) ^ ((lane >> 1) & 3)) * 8);  // swizzled read slot

#define STAGE_GU(AS, BGS, BUS, kt)           \
  {                                          \
    load_lds16(aptr0 + (kt), (AS) + d0);     \
    load_lds16(aptr1 + (kt), (AS) + d1);     \
    load_lds16(gptr0 + (kt), (BGS) + d0);    \
    load_lds16(gptr1 + (kt), (BGS) + d1);    \
    load_lds16(uptr0 + (kt), (BUS) + d0);    \
    load_lds16(uptr1 + (kt), (BUS) + d1);    \
  }

#define COMPUTE_GU(AS, BGS, BUS)                                                       \
  {                                                                                    \
    bf16x8 af[4], bg[4], bu[4];                                                        \
    _Pragma("unroll") for (int i = 0; i < 4; ++i) {                                    \
      af[i] = *reinterpret_cast<const bf16x8*>((AS) + (wm + i * 16 + fr) * 32 + cs);   \
      bg[i] = *reinterpret_cast<const bf16x8*>((BGS) + (wn + i * 16 + fr) * 32 + cs);  \
      bu[i] = *reinterpret_cast<const bf16x8*>((BUS) + (wn + i * 16 + fr) * 32 + cs);  \
    }                                                                                  \
    _Pragma("unroll") for (int i = 0; i < 4; ++i)                                      \
      _Pragma("unroll") for (int j = 0; j < 4; ++j) {                                  \
        accG[i][j] = __builtin_amdgcn_mfma_f32_16x16x32_bf16(af[i], bg[j], accG[i][j], 0, 0, 0); \
        accU[i][j] = __builtin_amdgcn_mfma_f32_16x16x32_bf16(af[i], bu[j], accU[i][j], 0, 0, 0); \
      }                                                                                \
  }

  STAGE_GU(As0, Bg0, Bu0, 0);
  SYNC_PIPE
#pragma unroll 1
  for (int kt = 0; kt < HID; kt += 64) {
    STAGE_GU(As1, Bg1, Bu1, kt + 32);   // prefetch next half, in flight across compute
    COMPUTE_GU(As0, Bg0, Bu0);
    SYNC_PIPE
    if (kt + 64 < HID) STAGE_GU(As0, Bg0, Bu0, kt + 64);
    COMPUTE_GU(As1, Bg1, Bu1);
    SYNC_PIPE
  }
#undef STAGE_GU
#undef COMPUTE_GU

  // epilogue: h = silu(g) * u (fp32 g), bf16 store. D frag: row=(lane>>4)*4+reg, col=lane&15
  const int lr = (lane >> 4) * 4;
  const int lc = lane & 15;
#pragma unroll
  for (int i = 0; i < 4; ++i) {
#pragma unroll
    for (int r = 0; r < 4; ++r) {
      int m = wm + i * 16 + lr + r;
      if (m0 + m < cnt) {
        size_t base = (size_t)(off + m0 + m) * INTER + (size_t)(n0 + wn + lc);
#pragma unroll
        for (int j = 0; j < 4; ++j) {
          float g = accG[i][j][r];
          float u = accU[i][j][r];
          float h = g / (1.f + __expf(-g)) * u;
          Hf[base + j * 16] = f2bf(h);
        }
      }
    }
  }
}

// ---------------- down-proj GEMM: Yf[slot] = w * (H Wd^T), same pipeline ----------------
__global__ __launch_bounds__(256, 3) void gemm_y_kernel(
    const unsigned short* __restrict__ Hf,   // [2*NTOK][INTER] bf16
    const unsigned short* __restrict__ Wd,   // [E][HID][INTER] bf16
    const int* __restrict__ counts, const int* __restrict__ offsets,
    const float* __restrict__ w_flat,
    const int* __restrict__ tile_map, const int* __restrict__ n_tiles,
    unsigned short* __restrict__ Yf) {       // [2*NTOK][HID] bf16
  const int bid = blockIdx.x;
  const int cpx = gridDim.x >> 3;            // 2304/8 = 288
  const int wg = (bid & 7) * cpx + (bid >> 3);
  const int y = wg / 16;
  if (y >= *n_tiles) return;
  const int xb = wg - y * 16;
  const int tm = tile_map[y];
  const int e = tm >> 16, m0 = tm & 0xFFFF;
  const int cnt = counts[e];
  const int off = offsets[e];
  const int n0 = xb * 128;

  __shared__ __align__(16) unsigned short As0[128 * 32], As1[128 * 32];
  __shared__ __align__(16) unsigned short Bs0[128 * 32], Bs1[128 * 32];

  const int tid = threadIdx.x;
  const int lane = tid & 63;
  const int wid = tid >> 6;
  const int rl = tid >> 2;
  const int srcc = ((tid & 3) ^ ((tid >> 3) & 3)) * 8;
  const int d0 = tid * 8;
  const int d1 = d0 + 64 * 32;

  const int r0 = m0 + rl, r1 = r0 + 64;
  const int s0 = (r0 < cnt) ? off + r0 : off;
  const int s1 = (r1 < cnt) ? off + r1 : off;
  const unsigned short* aptr0 = Hf + (size_t)s0 * INTER + srcc;
  const unsigned short* aptr1 = Hf + (size_t)s1 * INTER + srcc;
  const unsigned short* bptr0 = Wd + ((size_t)e * HID + n0 + rl) * INTER + srcc;
  const unsigned short* bptr1 = bptr0 + (size_t)64 * INTER;

  f32x4 zero = {0.f, 0.f, 0.f, 0.f};
  f32x4 acc[4][4];
#pragma unroll
  for (int i = 0; i < 4; ++i)
#pragma unroll
    for (int j = 0; j < 4; ++j) acc[i][j] = zero;

  const int wm = (wid >> 1) * 64;
  const int wn = (wid & 1) * 64;
  const int fr = lane & 15;
  const int cs = (((lane >> 4) ^ ((lane >> 1) & 3)) * 8);

#define STAGE_Y(AS, BS, kt)               \
  {                                       \
    load_lds16(aptr0 + (kt), (AS) + d0);  \
    load_lds16(aptr1 + (kt), (AS) + d1);  \
    load_lds16(bptr0 + (kt), (BS) + d0);  \
    load_lds16(bptr1 + (kt), (BS) + d1);  \
  }

#define COMPUTE_Y(AS, BS)                                                              \
  {                                                                                    \
    bf16x8 af[4], bf_[4];                                                              \
    _Pragma("unroll") for (int i = 0; i < 4; ++i) {                                    \
      af[i] = *reinterpret_cast<const bf16x8*>((AS) + (wm + i * 16 + fr) * 32 + cs);   \
      bf_[i] = *reinterpret_cast<const bf16x8*>((BS) + (wn + i * 16 + fr) * 32 + cs);  \
    }                                                                                  \
    _Pragma("unroll") for (int i = 0; i < 4; ++i)                                      \
      _Pragma("unroll") for (int j = 0; j < 4; ++j)                                    \
        acc[i][j] = __builtin_amdgcn_mfma_f32_16x16x32_bf16(af[i], bf_[j], acc[i][j], 0, 0, 0); \
  }

  STAGE_Y(As0, Bs0, 0);
  SYNC_PIPE
#pragma unroll 1
  for (int kt = 0; kt < INTER; kt += 64) {
    STAGE_Y(As1, Bs1, kt + 32);
    COMPUTE_Y(As0, Bs0);
    SYNC_PIPE
    if (kt + 64 < INTER) STAGE_Y(As0, Bs0, kt + 64);
    COMPUTE_Y(As1, Bs1);
    SYNC_PIPE
  }
#undef STAGE_Y
#undef COMPUTE_Y

  const int lr = (lane >> 4) * 4;
  const int lc = lane & 15;
#pragma unroll
  for (int i = 0; i < 4; ++i) {
#pragma unroll
    for (int r = 0; r < 4; ++r) {
      int m = wm + i * 16 + lr + r;
      if (m0 + m < cnt) {
        int slot = off + m0 + m;
        float w = w_flat[slot];
        size_t base = (size_t)slot * HID + (size_t)(n0 + wn + lc);
#pragma unroll
        for (int j = 0; j < 4; ++j) Yf[base + j * 16] = f2bf(w * acc[i][j][r]);
      }
    }
  }
}

// ---------------- combine: out[t] = Yf[slot0] + Yf[slot1] ----------------
__global__ __launch_bounds__(256) void combine_kernel(const unsigned short* __restrict__ Yf,
                                                      const int* __restrict__ tok_slot,
                                                      float* __restrict__ out) {
  const int t = blockIdx.x;
  const int c = threadIdx.x * 8;
  const int s0 = tok_slot[2 * t];
  const int s1 = tok_slot[2 * t + 1];
  const ushort4* p0 = reinterpret_cast<const ushort4*>(Yf + (size_t)s0 * HID + c);
  const ushort4* p1 = reinterpret_cast<const ushort4*>(Yf + (size_t)s1 * HID + c);
  ushort4 a0 = p0[0], a1 = p0[1];
  ushort4 b0 = p1[0], b1 = p1[1];
  float4 o0, o1;
  o0.x = bf2f(a0.x) + bf2f(b0.x);
  o0.y = bf2f(a0.y) + bf2f(b0.y);
  o0.z = bf2f(a0.z) + bf2f(b0.z);
  o0.w = bf2f(a0.w) + bf2f(b0.w);
  o1.x = bf2f(a1.x) + bf2f(b1.x);
  o1.y = bf2f(a1.y) + bf2f(b1.y);
  o1.z = bf2f(a1.z) + bf2f(b1.z);
  o1.w = bf2f(a1.w) + bf2f(b1.w);
  float4* op = reinterpret_cast<float4*>(out + (size_t)t * HID + c);
  op[0] = o0;
  op[1] = o1;
}

// ---------------- launch ----------------
extern "C" void kernel_launch(void* const* d_in, const int* in_sizes, int n_in,
                              void* d_out, int out_size, void* d_ws, size_t ws_size,
                              hipStream_t stream) {
  const float* x  = (const float*)d_in[0];
  const float* gw = (const float*)d_in[1];
  const float* wg = (const float*)d_in[2];
  const float* wu = (const float*)d_in[3];
  const float* wd = (const float*)d_in[4];
  float* out = (float*)d_out;
  char* ws = (char*)d_ws;

  // ws layout (bytes) — identical to r7-passing layout
  int*   counts   = (int*)(ws + 0);          // 64
  int*   offsets  = (int*)(ws + 128);        // 64
  int*   n_tiles  = (int*)(ws + 192);        // 4
  int*   tile_map = (int*)(ws + 256);        // <=144*4
  int*   te       = (int*)(ws + 1024);       // 64 KiB
  float* tw       = (float*)(ws + 66560);    // 64 KiB
  int*   tok_flat = (int*)(ws + 132096);     // 64 KiB
  float* w_flat   = (float*)(ws + 197632);   // 64 KiB
  unsigned short* Xb  = (unsigned short*)(ws + 263168);     // 32 MiB
  unsigned short* Wgb = (unsigned short*)(ws + 33817600);   // 48 MiB
  unsigned short* Wub = (unsigned short*)(ws + 84149248);   // 48 MiB
  unsigned short* Wdb = (unsigned short*)(ws + 134480896);  // 48 MiB
  unsigned short* Hf  = (unsigned short*)(ws + 184812544);  // 24 MiB
  int*   tok_slot = (int*)(ws + 209978368);  // 64 KiB
  // Yf [16384][2048] bf16 = 64 MiB, aliases Wgb+Wub (dead after gemm_gu)
  unsigned short* Yf  = Wgb;

  cvt3_kernel<<<dim3(1024, 3), 256, 0, stream>>>(wg, wu, wd, Wgb, Wub, Wdb,
                                                 NEXP * INTER * HID);

  router_kernel<<<NTOK / 8, 256, 0, stream>>>(x, gw, te, tw, Xb);
  build_kernel<<<1, 256, 0, stream>>>(te, tw, counts, offsets, tok_flat, w_flat,
                                      tok_slot, tile_map, n_tiles);

  gemm_gu_kernel<<<144 * 6, 256, 0, stream>>>(
      Xb, Wgb, Wub, counts, offsets, tok_flat, tile_map, n_tiles, Hf);
  gemm_y_kernel<<<144 * 16, 256, 0, stream>>>(
      Hf, Wdb, counts, offsets, w_flat, tile_map, n_tiles, Yf);
  combine_kernel<<<NTOK, 256, 0, stream>>>(Yf, tok_slot, out);
}